// Round 10
// baseline (405.872 us; speedup 1.0000x reference)
//
#include <hip/hip_runtime.h>
#include <hip/hip_bf16.h>

// x: (2,3,512,512) fp32 -> conv1 s2 p1 -> h: chunked layout [b][4][256][256][16]
// off conv: 3x3 p1, 64->20: K-split across waves (wave=16ch chunk, same 2-row tile),
//           LDS partial-sum reduce, fused group-sum atomics. grid 1024, 2 blk/CU.
// k_dsc: GN+tanh inline from raw sums, 2-pt lerp + K=5 conv -> cat (2,65536,16)
// final: GN (from raw sums) + 1x1 conv 16->64 + BN + ReLU -> fp32 NCHW

#define EPSF 1e-5f

typedef __attribute__((ext_vector_type(4))) float f4;

// h element index: ((b*4 + chunk)*65536 + i*256 + j)*16 + c   (c in 0..15)
// raw stats ws area: raw[0..39] offset groups {s,s2} x20 (gid=branch*10+b*5+g)
//                    raw2[0..15] cat groups {s,s2} x8     (gid=b*4+branch*2+g)

// ---------------- Kernel 1: conv1 + bn1 + relu -> h chunked ------------------
__global__ __launch_bounds__(256) void k_conv1(
    const float* __restrict__ x, const float* __restrict__ w,
    const float* __restrict__ g, const float* __restrict__ bb,
    const float* __restrict__ m, const float* __restrict__ v,
    float* __restrict__ h, float* __restrict__ statsraw)
{
    __shared__ float wl[27 * 64];            // [tap][oc]
    __shared__ float scale[64], shift[64];
    int t = threadIdx.x;
    if (blockIdx.x == 0 && t < 64) statsraw[t] = 0.f;   // zero raw(40)+raw2(16)
    for (int idx = t; idx < 1728; idx += 256) {
        int tap = idx >> 6, oc = idx & 63;
        wl[idx] = w[oc * 27 + tap];
    }
    if (t < 64) {
        float sc = g[t] * rsqrtf(v[t] + EPSF);
        scale[t] = sc; shift[t] = bb[t] - m[t] * sc;
    }
    __syncthreads();
    int lane = t & 63, wid = t >> 6;
    int blk = blockIdx.x;
    int b = blk >> 9;
    int rem = blk & 511;
    int i0 = (rem >> 2) * 2;
    int j0 = (rem & 3) * 64;
    int j = j0 + lane;
    f4 acc[2][4];
    #pragma unroll
    for (int r = 0; r < 2; ++r)
        #pragma unroll
        for (int q = 0; q < 4; ++q) acc[r][q] = (f4)0.f;
    #pragma unroll
    for (int ic = 0; ic < 3; ++ic) {
        #pragma unroll
        for (int dy = 0; dy < 3; ++dy) {
            const float* rowp[2]; bool vy[2];
            #pragma unroll
            for (int r = 0; r < 2; ++r) {
                int y = 2 * (i0 + r) + dy - 1;
                vy[r] = (unsigned)y < 512u;
                rowp[r] = x + ((size_t)(b * 3 + ic) * 512 + (vy[r] ? y : 0)) * 512;
            }
            #pragma unroll
            for (int dx = 0; dx < 3; ++dx) {
                int xx = 2 * j + dx - 1;
                bool vx = (unsigned)xx < 512u;
                int tap = ic * 9 + dy * 3 + dx;
                f4 w4[4];
                #pragma unroll
                for (int q = 0; q < 4; ++q)
                    w4[q] = *(const f4*)&wl[tap * 64 + wid * 16 + q * 4];
                #pragma unroll
                for (int r = 0; r < 2; ++r) {
                    float xv = (vy[r] && vx) ? rowp[r][xx] : 0.f;
                    #pragma unroll
                    for (int q = 0; q < 4; ++q) acc[r][q] += xv * w4[q];
                }
            }
        }
    }
    #pragma unroll
    for (int r = 0; r < 2; ++r) {
        size_t ij = (size_t)(i0 + r) * 256 + j;
        float* hp = h + ((size_t)(b * 4 + wid) * 65536 + ij) * 16;
        #pragma unroll
        for (int q = 0; q < 4; ++q) {
            f4 sc = *(const f4*)&scale[wid * 16 + q * 4];
            f4 sh = *(const f4*)&shift[wid * 16 + q * 4];
            f4 val = acc[r][q] * sc + sh;
            f4 rv;
            #pragma unroll
            for (int e = 0; e < 4; ++e) rv[e] = fmaxf(val[e], 0.f);
            *(f4*)(hp + q * 4) = rv;
        }
    }
}

// ---------------- Kernel 2: offset convs, K-split across waves ----------------
// block = 256 (4 waves); tile 64 j (lanes) x 2 i rows (all waves, same rows);
// wave wid computes partial sums over channels 16*wid..16*wid+15. grid = 1024.
__global__ __launch_bounds__(256, 2) void k_offconv(
    const float* __restrict__ h,
    const float* __restrict__ wx, const float* __restrict__ wy,
    const float* __restrict__ bx, const float* __restrict__ by,
    float* __restrict__ offx, float* __restrict__ offy,
    float* __restrict__ raw)
{
    __shared__ float wl[9 * 64 * 20];        // [tap][c][o20]  (46080 B)
    __shared__ float red[3 * 2 * 64 * 20];   // [wave-1][r][lane][o20] (30720 B)
    __shared__ float bias[20];
    int t = threadIdx.x;
    for (int idx = t; idx < 11520; idx += 256) {
        int o = idx % 20;
        int rest = idx / 20;                 // tap*64 + c
        int c = rest & 63, tap = rest >> 6;
        wl[idx] = (o < 10) ? wx[((size_t)o * 64 + c) * 9 + tap]
                           : wy[((size_t)(o - 10) * 64 + c) * 9 + tap];
    }
    if (t < 20) bias[t] = (t < 10) ? bx[t] : by[t - 10];
    __syncthreads();
    int lane = t & 63, wid = t >> 6;
    int blk = blockIdx.x;
    int b = blk >> 9;
    int rem = blk & 511;
    int i0 = (rem >> 2) * 2;
    int j = (rem & 3) * 64 + lane;
    f4 acc[2][5];
    #pragma unroll
    for (int r = 0; r < 2; ++r)
        #pragma unroll
        for (int q = 0; q < 5; ++q) acc[r][q] = (f4)0.f;
    const float* hc = h + ((size_t)(b * 4 + wid) * 65536) * 16;   // this wave's chunk
    #pragma unroll 1
    for (int ky = 0; ky < 3; ++ky) {
        int y0 = i0 + ky - 1;
        int y1 = y0 + 1;
        bool vy0 = (unsigned)y0 < 256u;
        bool vy1 = (unsigned)y1 < 256u;
        const float* rp0 = hc + (size_t)(vy0 ? y0 : 0) * 256 * 16;
        const float* rp1 = hc + (size_t)(vy1 ? y1 : 0) * 256 * 16;
        #pragma unroll 1
        for (int kx = 0; kx < 3; ++kx) {
            int xx = j + kx - 1;
            bool vx = (unsigned)xx < 256u;
            size_t colofs = (size_t)(vx ? xx : 0) * 16;
            const float* wt = &wl[((ky * 3 + kx) * 64 + wid * 16) * 20];
            #pragma unroll 2
            for (int cq = 0; cq < 4; ++cq) {
                f4 h0 = (vy0 && vx) ? *(const f4*)(rp0 + colofs + cq * 4) : (f4)0.f;
                f4 h1 = (vy1 && vx) ? *(const f4*)(rp1 + colofs + cq * 4) : (f4)0.f;
                #pragma unroll
                for (int ci = 0; ci < 4; ++ci) {
                    const float* wr = &wt[(cq * 4 + ci) * 20];
                    f4 w0 = *(const f4*)&wr[0];
                    f4 w1 = *(const f4*)&wr[4];
                    f4 w2 = *(const f4*)&wr[8];
                    f4 w3 = *(const f4*)&wr[12];
                    f4 w4v = *(const f4*)&wr[16];
                    float a0 = h0[ci], a1 = h1[ci];
                    acc[0][0] += a0 * w0;
                    acc[0][1] += a0 * w1;
                    acc[0][2] += a0 * w2;
                    acc[0][3] += a0 * w3;
                    acc[0][4] += a0 * w4v;
                    acc[1][0] += a1 * w0;
                    acc[1][1] += a1 * w1;
                    acc[1][2] += a1 * w2;
                    acc[1][3] += a1 * w3;
                    acc[1][4] += a1 * w4v;
                }
            }
        }
    }
    // cross-wave K reduction via LDS
    if (wid > 0) {
        float* rb = &red[(size_t)(wid - 1) * 2560];
        #pragma unroll
        for (int r = 0; r < 2; ++r)
            #pragma unroll
            for (int q = 0; q < 5; ++q)
                *(f4*)&rb[(r * 64 + lane) * 20 + q * 4] = acc[r][q];
    }
    __syncthreads();
    if (wid == 0) {
        #pragma unroll
        for (int w_ = 0; w_ < 3; ++w_) {
            const float* rb = &red[(size_t)w_ * 2560];
            #pragma unroll
            for (int r = 0; r < 2; ++r)
                #pragma unroll
                for (int q = 0; q < 5; ++q)
                    acc[r][q] += *(const f4*)&rb[(r * 64 + lane) * 20 + q * 4];
        }
        // epilogue: bias, store, per-oc {sum,sumsq} -> shuffle -> atomics
        float sv[20], qv[20];
        #pragma unroll
        for (int o = 0; o < 20; ++o) { sv[o] = 0.f; qv[o] = 0.f; }
        #pragma unroll
        for (int r = 0; r < 2; ++r) {
            size_t p = (size_t)b * 65536 + (size_t)(i0 + r) * 256 + j;
            float* ox = offx + p * 10;
            float* oy = offy + p * 10;
            #pragma unroll
            for (int q = 0; q < 5; ++q)
                #pragma unroll
                for (int e = 0; e < 4; ++e) {
                    int o = q * 4 + e;
                    float val = acc[r][q][e] + bias[o];
                    sv[o] += val; qv[o] += val * val;
                    if (o < 10) ox[o] = val; else oy[o - 10] = val;
                }
        }
        #pragma unroll
        for (int d = 32; d >= 1; d >>= 1)
            #pragma unroll
            for (int o = 0; o < 20; ++o) {
                sv[o] += __shfl_xor(sv[o], d, 64);
                qv[o] += __shfl_xor(qv[o], d, 64);
            }
        if (lane < 20) {
            int o = lane;
            float ss = __shfl(sv[o], 0, 64);
            float qq = __shfl(qv[o], 0, 64);
            // note: after butterfly all lanes hold the total, so lane-local is fine:
            ss = sv[o]; qq = qv[o];
            int branch = o < 10 ? 0 : 1;
            int c = o - branch * 10;
            int gid = branch * 10 + b * 5 + (c >> 1);
            atomicAdd(&raw[gid * 2], ss);
            atomicAdd(&raw[gid * 2 + 1], qq);
        }
    }
}

// ---------------- Kernel 3: GN+tanh inline + 2pt-lerp + deform conv -----------
// block = 256; tile 64 j (lanes) x 8 i (4 waves x 2 rows). grid (256,2).
__global__ __launch_bounds__(256) void k_dsc(
    const float* __restrict__ h,
    const float* __restrict__ offx, const float* __restrict__ offy,
    const float* __restrict__ raw,
    const float* __restrict__ gx, const float* __restrict__ bxg,
    const float* __restrict__ gy, const float* __restrict__ byg,
    const float* __restrict__ wx_, const float* __restrict__ wy_,
    const float* __restrict__ bx_, const float* __restrict__ by_,
    float* __restrict__ cat,
    float* __restrict__ raw2)
{
    int branch = blockIdx.y;
    __shared__ float wl[2560];               // [k][c][oc8]
    __shared__ float bias[8];
    const float* wsrc = branch ? wy_ : wx_;
    int t = threadIdx.x;
    for (int idx = t; idx < 2560; idx += 256) {
        int oc = idx & 7;
        int rest = idx >> 3;                 // k*64 + c
        wl[idx] = wsrc[(size_t)oc * 320 + (rest & 63) * 5 + (rest >> 6)];
    }
    if (t < 8) bias[t] = (branch ? by_ : bx_)[t];
    __syncthreads();
    int lane = t & 63, wid = t >> 6;
    int blk = blockIdx.x;
    int b = blk >> 7;
    int rem = blk & 127;
    int i0 = (rem >> 2) * 8 + wid * 2;
    int j = (rem & 3) * 64 + lane;
    const float* offarr = branch ? offy : offx;
    const float* goff = branch ? gy : gx;
    const float* boff = branch ? byg : bxg;
    int cbase = branch * 5;
    const int idxs[4] = {0, 1, 3, 4};
    float mn[4], rs[4], gm[4], bt[4];
    #pragma unroll
    for (int u = 0; u < 4; ++u) {
        int c = cbase + idxs[u];
        int g = c >> 1;
        int sidx = branch * 10 + b * 5 + g;
        float ss = raw[sidx * 2], qq = raw[sidx * 2 + 1];
        float mean = ss * (1.f / 131072.f);
        float var = qq * (1.f / 131072.f) - mean * mean;
        mn[u] = mean; rs[u] = rsqrtf(var + EPSF);
        gm[u] = goff[c]; bt[u] = boff[c];
    }
    float cum[2][5];
    #pragma unroll
    for (int r = 0; r < 2; ++r) {
        size_t p = (size_t)b * 65536 + (size_t)(i0 + r) * 256 + j;
        const float* op = offarr + p * 10 + cbase;
        float tv[4];
        #pragma unroll
        for (int u = 0; u < 4; ++u)
            tv[u] = tanhf((op[idxs[u]] - mn[u]) * rs[u] * gm[u] + bt[u]);
        cum[r][0] = tv[0] + tv[1]; cum[r][1] = tv[1]; cum[r][2] = 0.f;
        cum[r][3] = tv[2]; cum[r][4] = tv[2] + tv[3];
    }
    f4 acc[2][2];
    #pragma unroll
    for (int r = 0; r < 2; ++r) { acc[r][0] = (f4)0.f; acc[r][1] = (f4)0.f; }
    #pragma unroll 1
    for (int k = 0; k < 5; ++k) {
        int pixA[2], pixB[2]; float fr[2];
        #pragma unroll
        for (int r = 0; r < 2; ++r) {
            int i = i0 + r;
            if (branch == 0) {
                float yf = (float)i + cum[r][k];
                yf = fminf(fmaxf(yf, 0.f), 255.f);
                float y0 = floorf(yf);
                fr[r] = yf - y0;
                int y0i = (int)y0;
                int y1i = min(y0i + 1, 255);
                int xi = min(max(j + k - 2, 0), 255);
                pixA[r] = y0i * 256 + xi;
                pixB[r] = y1i * 256 + xi;
            } else {
                float xf = (float)j + cum[r][k];
                xf = fminf(fmaxf(xf, 0.f), 255.f);
                float x0 = floorf(xf);
                fr[r] = xf - x0;
                int x0i = (int)x0;
                int x1i = min(x0i + 1, 255);
                int yi = min(max(i + k - 2, 0), 255);
                pixA[r] = yi * 256 + x0i;
                pixB[r] = yi * 256 + x1i;
            }
        }
        #pragma unroll 1
        for (int chunk = 0; chunk < 4; ++chunk) {
            const float* hc = h + ((size_t)(b * 4 + chunk) * 65536) * 16;
            const float* wk = &wl[((size_t)k * 64 + chunk * 16) * 8];
            f4 bufA[2][4], bufB[2][4];
            #pragma unroll
            for (int r = 0; r < 2; ++r)
                #pragma unroll
                for (int cq = 0; cq < 4; ++cq) {
                    bufA[r][cq] = *(const f4*)(hc + (size_t)pixA[r] * 16 + cq * 4);
                    bufB[r][cq] = *(const f4*)(hc + (size_t)pixB[r] * 16 + cq * 4);
                }
            f4 vf[2][4];
            #pragma unroll
            for (int r = 0; r < 2; ++r)
                #pragma unroll
                for (int cq = 0; cq < 4; ++cq)
                    vf[r][cq] = bufA[r][cq] + fr[r] * (bufB[r][cq] - bufA[r][cq]);
            #pragma unroll
            for (int cq = 0; cq < 4; ++cq)
                #pragma unroll
                for (int ci = 0; ci < 4; ++ci) {
                    f4 w0 = *(const f4*)&wk[(cq * 4 + ci) * 8];
                    f4 w1 = *(const f4*)&wk[(cq * 4 + ci) * 8 + 4];
                    #pragma unroll
                    for (int r = 0; r < 2; ++r) {
                        acc[r][0] += vf[r][cq][ci] * w0;
                        acc[r][1] += vf[r][cq][ci] * w1;
                    }
                }
        }
    }
    float sg0 = 0.f, sq0 = 0.f, sg1 = 0.f, sq1 = 0.f;
    #pragma unroll
    for (int r = 0; r < 2; ++r) {
        size_t p = (size_t)b * 65536 + (size_t)(i0 + r) * 256 + j;
        f4 v0 = acc[r][0] + *(const f4*)&bias[0];
        f4 v1 = acc[r][1] + *(const f4*)&bias[4];
        *(f4*)&cat[p * 16 + branch * 8] = v0;
        *(f4*)&cat[p * 16 + branch * 8 + 4] = v1;
        #pragma unroll
        for (int e = 0; e < 4; ++e) {
            sg0 += v0[e]; sq0 += v0[e] * v0[e];
            sg1 += v1[e]; sq1 += v1[e] * v1[e];
        }
    }
    #pragma unroll
    for (int d = 32; d >= 1; d >>= 1) {
        sg0 += __shfl_xor(sg0, d, 64); sq0 += __shfl_xor(sq0, d, 64);
        sg1 += __shfl_xor(sg1, d, 64); sq1 += __shfl_xor(sq1, d, 64);
    }
    if (lane == 0) {
        int g0 = b * 4 + branch * 2;
        atomicAdd(&raw2[g0 * 2], sg0);
        atomicAdd(&raw2[g0 * 2 + 1], sq0);
        atomicAdd(&raw2[(g0 + 1) * 2], sg1);
        atomicAdd(&raw2[(g0 + 1) * 2 + 1], sq1);
    }
}

// ---------------- Kernel 4: GN+relu + 1x1 conv + bn2 + relu -> fp32 out -------
__global__ __launch_bounds__(256) void k_final(
    const float* __restrict__ cat,
    const float* __restrict__ raw2,
    const float* __restrict__ gnx_g, const float* __restrict__ gnx_b,
    const float* __restrict__ gny_g, const float* __restrict__ gny_b,
    const float* __restrict__ w2,
    const float* __restrict__ g2, const float* __restrict__ b2,
    const float* __restrict__ m2, const float* __restrict__ v2,
    float* __restrict__ out)
{
    __shared__ float wl[1024];
    __shared__ float sc2[64], sh2[64];
    __shared__ float cmean[16], crstd[16], cg[16], cb[16];
    int t = threadIdx.x;
    int pbase = blockIdx.x * 64;
    int b = pbase >> 16;
    for (int idx = t; idx < 1024; idx += 256) wl[idx] = w2[idx];
    if (t < 64) {
        float sc = g2[t] * rsqrtf(v2[t] + EPSF);
        sc2[t] = sc;
        sh2[t] = b2[t] - m2[t] * sc;
    }
    if (t < 16) {
        int branch = t >> 3; int cc = t & 7; int g = cc >> 2;
        int sidx = b * 4 + branch * 2 + g;
        float ss = raw2[sidx * 2], qq = raw2[sidx * 2 + 1];
        float mean = ss * (1.f / 262144.f);
        float var = qq * (1.f / 262144.f) - mean * mean;
        cmean[t] = mean;
        crstd[t] = rsqrtf(var + EPSF);
        cg[t] = branch ? gny_g[cc] : gnx_g[cc];
        cb[t] = branch ? gny_b[cc] : gnx_b[cc];
    }
    __syncthreads();
    int lane = t & 63, wq = t >> 6;
    int p = pbase + lane;
    int ij = p & 65535;
    float vv[16];
    const float* cp = &cat[(size_t)p * 16];
    #pragma unroll
    for (int c = 0; c < 16; ++c) {
        float x = (cp[c] - cmean[c]) * crstd[c] * cg[c] + cb[c];
        vv[c] = fmaxf(x, 0.f);
    }
    #pragma unroll
    for (int q = 0; q < 16; ++q) {
        int oc = wq + q * 4;
        float s = 0.f;
        #pragma unroll
        for (int c = 0; c < 16; ++c) s += vv[c] * wl[oc * 16 + c];
        float r = fmaxf(s * sc2[oc] + sh2[oc], 0.f);
        out[((size_t)(b * 64 + oc) << 16) + ij] = r;
    }
}

extern "C" void kernel_launch(void* const* d_in, const int* in_sizes, int n_in,
                              void* d_out, int out_size, void* d_ws, size_t ws_size,
                              hipStream_t stream) {
    const float* x       = (const float*)d_in[0];
    const float* conv1_w = (const float*)d_in[1];
    const float* bn1_g   = (const float*)d_in[2];
    const float* bn1_b   = (const float*)d_in[3];
    const float* bn1_m   = (const float*)d_in[4];
    const float* bn1_v   = (const float*)d_in[5];
    const float* offx_w  = (const float*)d_in[6];
    const float* offx_b  = (const float*)d_in[7];
    const float* gnoffx_g= (const float*)d_in[8];
    const float* gnoffx_b= (const float*)d_in[9];
    const float* dscx_w  = (const float*)d_in[10];
    const float* dscx_b  = (const float*)d_in[11];
    const float* gnx_g   = (const float*)d_in[12];
    const float* gnx_b   = (const float*)d_in[13];
    const float* offy_w  = (const float*)d_in[14];
    const float* offy_b  = (const float*)d_in[15];
    const float* gnoffy_g= (const float*)d_in[16];
    const float* gnoffy_b= (const float*)d_in[17];
    const float* dscy_w  = (const float*)d_in[18];
    const float* dscy_b  = (const float*)d_in[19];
    const float* gny_g   = (const float*)d_in[20];
    const float* gny_b   = (const float*)d_in[21];
    const float* conv2_w = (const float*)d_in[22];
    const float* bn2_g   = (const float*)d_in[23];
    const float* bn2_b   = (const float*)d_in[24];
    const float* bn2_m   = (const float*)d_in[25];
    const float* bn2_v   = (const float*)d_in[26];

    float* ws = (float*)d_ws;
    float* h        = ws;                       // 8,388,608
    float* offx     = h + 8388608;              // 1,310,720
    float* offy     = offx + 1310720;           // 1,310,720
    float* cat      = offy + 1310720;           // 2,097,152
    float* raw      = cat + 2097152;            // 40 offset sums
    float* raw2     = raw + 40;                 // 16 cat sums (zeroed as 64 total)

    k_conv1<<<1024, 256, 0, stream>>>(x, conv1_w, bn1_g, bn1_b, bn1_m, bn1_v, h, raw);
    k_offconv<<<1024, 256, 0, stream>>>(h, offx_w, offy_w, offx_b, offy_b,
                                        offx, offy, raw);
    k_dsc<<<dim3(256, 2), 256, 0, stream>>>(h, offx, offy, raw,
                                            gnoffx_g, gnoffx_b, gnoffy_g, gnoffy_b,
                                            dscx_w, dscy_w, dscx_b, dscy_b,
                                            cat, raw2);
    k_final<<<2048, 256, 0, stream>>>(cat, raw2, gnx_g, gnx_b, gny_g, gny_b,
                                      conv2_w, bn2_g, bn2_b, bn2_m, bn2_v,
                                      (float*)d_out);
}

// Round 11
// 355.631 us; speedup vs baseline: 1.1413x; 1.1413x over previous
//
#include <hip/hip_runtime.h>
#include <hip/hip_bf16.h>

// x: (2,3,512,512) fp32 -> conv1 s2 p1 -> h: chunked layout [b][4][256][256][16]
// off conv: 3x3 p1, 64->20: R=4 rows/thread, 128-thr blocks (2 waves), grid 256,
//           6-row register window, LDS weights, fused group-sum atomics
// k_dsc: 1 row/thread, grid (512,2) (4 blk/CU), GN+tanh inline, 2-pt lerp + K=5 conv
// final: GN (from raw sums) + 1x1 conv 16->64 + BN + ReLU -> fp32 NCHW

#define EPSF 1e-5f

typedef __attribute__((ext_vector_type(4))) float f4;

// h element index: ((b*4 + chunk)*65536 + i*256 + j)*16 + c   (c in 0..15)
// raw stats ws area: raw[0..39] offset groups {s,s2} x20 (gid=branch*10+b*5+g)
//                    raw2[0..15] cat groups {s,s2} x8     (gid=b*4+branch*2+g)

// ---------------- Kernel 1: conv1 + bn1 + relu -> h chunked ------------------
__global__ __launch_bounds__(256) void k_conv1(
    const float* __restrict__ x, const float* __restrict__ w,
    const float* __restrict__ g, const float* __restrict__ bb,
    const float* __restrict__ m, const float* __restrict__ v,
    float* __restrict__ h, float* __restrict__ statsraw)
{
    __shared__ float wl[27 * 64];            // [tap][oc]
    __shared__ float scale[64], shift[64];
    int t = threadIdx.x;
    if (blockIdx.x == 0 && t < 64) statsraw[t] = 0.f;   // zero raw(40)+raw2(16)
    for (int idx = t; idx < 1728; idx += 256) {
        int tap = idx >> 6, oc = idx & 63;
        wl[idx] = w[oc * 27 + tap];
    }
    if (t < 64) {
        float sc = g[t] * rsqrtf(v[t] + EPSF);
        scale[t] = sc; shift[t] = bb[t] - m[t] * sc;
    }
    __syncthreads();
    int lane = t & 63, wid = t >> 6;
    int blk = blockIdx.x;
    int b = blk >> 9;
    int rem = blk & 511;
    int i0 = (rem >> 2) * 2;
    int j0 = (rem & 3) * 64;
    int j = j0 + lane;
    f4 acc[2][4];
    #pragma unroll
    for (int r = 0; r < 2; ++r)
        #pragma unroll
        for (int q = 0; q < 4; ++q) acc[r][q] = (f4)0.f;
    #pragma unroll
    for (int ic = 0; ic < 3; ++ic) {
        #pragma unroll
        for (int dy = 0; dy < 3; ++dy) {
            const float* rowp[2]; bool vy[2];
            #pragma unroll
            for (int r = 0; r < 2; ++r) {
                int y = 2 * (i0 + r) + dy - 1;
                vy[r] = (unsigned)y < 512u;
                rowp[r] = x + ((size_t)(b * 3 + ic) * 512 + (vy[r] ? y : 0)) * 512;
            }
            #pragma unroll
            for (int dx = 0; dx < 3; ++dx) {
                int xx = 2 * j + dx - 1;
                bool vx = (unsigned)xx < 512u;
                int tap = ic * 9 + dy * 3 + dx;
                f4 w4[4];
                #pragma unroll
                for (int q = 0; q < 4; ++q)
                    w4[q] = *(const f4*)&wl[tap * 64 + wid * 16 + q * 4];
                #pragma unroll
                for (int r = 0; r < 2; ++r) {
                    float xv = (vy[r] && vx) ? rowp[r][xx] : 0.f;
                    #pragma unroll
                    for (int q = 0; q < 4; ++q) acc[r][q] += xv * w4[q];
                }
            }
        }
    }
    #pragma unroll
    for (int r = 0; r < 2; ++r) {
        size_t ij = (size_t)(i0 + r) * 256 + j;
        float* hp = h + ((size_t)(b * 4 + wid) * 65536 + ij) * 16;
        #pragma unroll
        for (int q = 0; q < 4; ++q) {
            f4 sc = *(const f4*)&scale[wid * 16 + q * 4];
            f4 sh = *(const f4*)&shift[wid * 16 + q * 4];
            f4 val = acc[r][q] * sc + sh;
            f4 rv;
            #pragma unroll
            for (int e = 0; e < 4; ++e) rv[e] = fmaxf(val[e], 0.f);
            *(f4*)(hp + q * 4) = rv;
        }
    }
}

// ---------------- Kernel 2: offset convs, R=4, 2-wave blocks ------------------
// block = 128 (2 waves); tile 64 j (lanes) x 8 i (2 waves x 4 rows). grid = 256.
// 6-row h register window reused across ky; weights LDS-broadcast (1440/wave).
__global__ __launch_bounds__(128, 1) void k_offconv(
    const float* __restrict__ h,
    const float* __restrict__ wx, const float* __restrict__ wy,
    const float* __restrict__ bx, const float* __restrict__ by,
    float* __restrict__ offx, float* __restrict__ offy,
    float* __restrict__ raw)
{
    __shared__ float wl[9 * 64 * 20];        // [tap][c][o20]
    __shared__ float bias[20];
    __shared__ float wsum[2][20][2];
    int t = threadIdx.x;
    for (int idx = t; idx < 11520; idx += 128) {
        int o = idx % 20;
        int rest = idx / 20;                 // tap*64 + c
        int c = rest & 63, tap = rest >> 6;
        wl[idx] = (o < 10) ? wx[((size_t)o * 64 + c) * 9 + tap]
                           : wy[((size_t)(o - 10) * 64 + c) * 9 + tap];
    }
    if (t < 20) bias[t] = (t < 10) ? bx[t] : by[t - 10];
    __syncthreads();
    int lane = t & 63, wid = t >> 6;        // wid in {0,1}
    int blk = blockIdx.x;
    int b = blk >> 7;
    int rem = blk & 127;
    int i0 = (rem >> 2) * 8 + wid * 4;      // wave owns rows i0..i0+3
    int j = (rem & 3) * 64 + lane;
    f4 acc[4][5];
    #pragma unroll
    for (int r = 0; r < 4; ++r)
        #pragma unroll
        for (int q = 0; q < 5; ++q) acc[r][q] = (f4)0.f;
    #pragma unroll 1
    for (int chunk = 0; chunk < 4; ++chunk) {
        const float* hc = h + ((size_t)(b * 4 + chunk) * 65536) * 16;
        #pragma unroll 1
        for (int kx = 0; kx < 3; ++kx) {
            int xx = j + kx - 1;
            bool vx = (unsigned)xx < 256u;
            const float* colp = hc + (size_t)(vx ? xx : 0) * 16;
            #pragma unroll 1
            for (int cq = 0; cq < 4; ++cq) {
                f4 hb[6];
                #pragma unroll
                for (int rr = 0; rr < 6; ++rr) {
                    int y = i0 + rr - 1;
                    bool vy = (unsigned)y < 256u;
                    hb[rr] = (vy && vx) ? *(const f4*)(colp + (size_t)y * 4096 + cq * 4)
                                        : (f4)0.f;
                }
                #pragma unroll
                for (int ky = 0; ky < 3; ++ky) {
                    const float* wt = &wl[((ky * 3 + kx) * 64 + chunk * 16 + cq * 4) * 20];
                    #pragma unroll
                    for (int ci = 0; ci < 4; ++ci) {
                        const float* wr = &wt[ci * 20];
                        f4 w0 = *(const f4*)&wr[0];
                        f4 w1 = *(const f4*)&wr[4];
                        f4 w2 = *(const f4*)&wr[8];
                        f4 w3 = *(const f4*)&wr[12];
                        f4 w4v = *(const f4*)&wr[16];
                        #pragma unroll
                        for (int r = 0; r < 4; ++r) {
                            float a = hb[r + ky][ci];
                            acc[r][0] += a * w0;
                            acc[r][1] += a * w1;
                            acc[r][2] += a * w2;
                            acc[r][3] += a * w3;
                            acc[r][4] += a * w4v;
                        }
                    }
                }
            }
        }
    }
    // epilogue: bias, store, per-oc {sum,sumsq} over 4 rows -> shuffle -> atomics
    float sv[20], qv[20];
    #pragma unroll
    for (int o = 0; o < 20; ++o) { sv[o] = 0.f; qv[o] = 0.f; }
    #pragma unroll
    for (int r = 0; r < 4; ++r) {
        size_t p = (size_t)b * 65536 + (size_t)(i0 + r) * 256 + j;
        float* ox = offx + p * 10;
        float* oy = offy + p * 10;
        #pragma unroll
        for (int q = 0; q < 5; ++q)
            #pragma unroll
            for (int e = 0; e < 4; ++e) {
                int o = q * 4 + e;
                float val = acc[r][q][e] + bias[o];
                sv[o] += val; qv[o] += val * val;
                if (o < 10) ox[o] = val; else oy[o - 10] = val;
            }
    }
    #pragma unroll
    for (int d = 32; d >= 1; d >>= 1)
        #pragma unroll
        for (int o = 0; o < 20; ++o) {
            sv[o] += __shfl_xor(sv[o], d, 64);
            qv[o] += __shfl_xor(qv[o], d, 64);
        }
    if (lane == 0)
        #pragma unroll
        for (int o = 0; o < 20; ++o) { wsum[wid][o][0] = sv[o]; wsum[wid][o][1] = qv[o]; }
    __syncthreads();
    if (t < 20) {
        float ss = wsum[0][t][0] + wsum[1][t][0];
        float qq = wsum[0][t][1] + wsum[1][t][1];
        int branch = t < 10 ? 0 : 1;
        int c = t - branch * 10;
        int gid = branch * 10 + b * 5 + (c >> 1);
        atomicAdd(&raw[gid * 2], ss);
        atomicAdd(&raw[gid * 2 + 1], qq);
    }
}

// ---------------- Kernel 3: GN+tanh inline + 2pt-lerp + deform conv -----------
// block = 256; tile 64 j (lanes) x 4 i (4 waves x 1 row). grid (512,2) = 4 blk/CU.
__global__ __launch_bounds__(256) void k_dsc(
    const float* __restrict__ h,
    const float* __restrict__ offx, const float* __restrict__ offy,
    const float* __restrict__ raw,
    const float* __restrict__ gx, const float* __restrict__ bxg,
    const float* __restrict__ gy, const float* __restrict__ byg,
    const float* __restrict__ wx_, const float* __restrict__ wy_,
    const float* __restrict__ bx_, const float* __restrict__ by_,
    float* __restrict__ cat,
    float* __restrict__ raw2)
{
    int branch = blockIdx.y;
    __shared__ float wl[2560];               // [k][c][oc8]
    __shared__ float bias[8];
    __shared__ float ws2[4][4];
    const float* wsrc = branch ? wy_ : wx_;
    int t = threadIdx.x;
    for (int idx = t; idx < 2560; idx += 256) {
        int oc = idx & 7;
        int rest = idx >> 3;                 // k*64 + c
        wl[idx] = wsrc[(size_t)oc * 320 + (rest & 63) * 5 + (rest >> 6)];
    }
    if (t < 8) bias[t] = (branch ? by_ : bx_)[t];
    __syncthreads();
    int lane = t & 63, wid = t >> 6;
    int blk = blockIdx.x;
    int b = blk >> 8;
    int rem = blk & 255;
    int i = (rem >> 2) * 4 + wid;           // 1 row per wave
    int j = (rem & 3) * 64 + lane;
    const float* offarr = branch ? offy : offx;
    const float* goff = branch ? gy : gx;
    const float* boff = branch ? byg : bxg;
    int cbase = branch * 5;
    const int idxs[4] = {0, 1, 3, 4};
    float cum[5];
    {
        size_t p = (size_t)b * 65536 + (size_t)i * 256 + j;
        const float* op = offarr + p * 10 + cbase;
        float tv[4];
        #pragma unroll
        for (int u = 0; u < 4; ++u) {
            int c = cbase + idxs[u];
            int g = c >> 1;
            int sidx = branch * 10 + b * 5 + g;
            float ss = raw[sidx * 2], qq = raw[sidx * 2 + 1];
            float mean = ss * (1.f / 131072.f);
            float var = qq * (1.f / 131072.f) - mean * mean;
            float val = (op[idxs[u]] - mean) * rsqrtf(var + EPSF) * goff[c] + boff[c];
            tv[u] = tanhf(val);
        }
        cum[0] = tv[0] + tv[1]; cum[1] = tv[1]; cum[2] = 0.f;
        cum[3] = tv[2]; cum[4] = tv[2] + tv[3];
    }
    f4 acc0 = (f4)0.f, acc1 = (f4)0.f;
    #pragma unroll 1
    for (int k = 0; k < 5; ++k) {
        int pixA, pixB; float fr;
        if (branch == 0) {
            float yf = (float)i + cum[k];
            yf = fminf(fmaxf(yf, 0.f), 255.f);
            float y0 = floorf(yf);
            fr = yf - y0;
            int y0i = (int)y0;
            int y1i = min(y0i + 1, 255);
            int xi = min(max(j + k - 2, 0), 255);
            pixA = y0i * 256 + xi;
            pixB = y1i * 256 + xi;
        } else {
            float xf = (float)j + cum[k];
            xf = fminf(fmaxf(xf, 0.f), 255.f);
            float x0 = floorf(xf);
            fr = xf - x0;
            int x0i = (int)x0;
            int x1i = min(x0i + 1, 255);
            int yi = min(max(i + k - 2, 0), 255);
            pixA = yi * 256 + x0i;
            pixB = yi * 256 + x1i;
        }
        #pragma unroll 1
        for (int chunk = 0; chunk < 4; ++chunk) {
            const float* hc = h + ((size_t)(b * 4 + chunk) * 65536) * 16;
            const float* wk = &wl[((size_t)k * 64 + chunk * 16) * 8];
            f4 bufA[4], bufB[4];
            #pragma unroll
            for (int cq = 0; cq < 4; ++cq) {
                bufA[cq] = *(const f4*)(hc + (size_t)pixA * 16 + cq * 4);
                bufB[cq] = *(const f4*)(hc + (size_t)pixB * 16 + cq * 4);
            }
            #pragma unroll
            for (int cq = 0; cq < 4; ++cq) {
                f4 vf = bufA[cq] + fr * (bufB[cq] - bufA[cq]);
                #pragma unroll
                for (int ci = 0; ci < 4; ++ci) {
                    f4 w0 = *(const f4*)&wk[(cq * 4 + ci) * 8];
                    f4 w1 = *(const f4*)&wk[(cq * 4 + ci) * 8 + 4];
                    acc0 += vf[ci] * w0;
                    acc1 += vf[ci] * w1;
                }
            }
        }
    }
    float sg0 = 0.f, sq0 = 0.f, sg1 = 0.f, sq1 = 0.f;
    {
        size_t p = (size_t)b * 65536 + (size_t)i * 256 + j;
        f4 v0 = acc0 + *(const f4*)&bias[0];
        f4 v1 = acc1 + *(const f4*)&bias[4];
        *(f4*)&cat[p * 16 + branch * 8] = v0;
        *(f4*)&cat[p * 16 + branch * 8 + 4] = v1;
        #pragma unroll
        for (int e = 0; e < 4; ++e) {
            sg0 += v0[e]; sq0 += v0[e] * v0[e];
            sg1 += v1[e]; sq1 += v1[e] * v1[e];
        }
    }
    #pragma unroll
    for (int d = 32; d >= 1; d >>= 1) {
        sg0 += __shfl_xor(sg0, d, 64); sq0 += __shfl_xor(sq0, d, 64);
        sg1 += __shfl_xor(sg1, d, 64); sq1 += __shfl_xor(sq1, d, 64);
    }
    if (lane == 0) {
        ws2[wid][0] = sg0; ws2[wid][1] = sq0; ws2[wid][2] = sg1; ws2[wid][3] = sq1;
    }
    __syncthreads();
    if (t < 4) {
        float val = ws2[0][t] + ws2[1][t] + ws2[2][t] + ws2[3][t];
        int g0 = b * 4 + branch * 2;
        int gi = g0 + (t >> 1);
        atomicAdd(&raw2[gi * 2 + (t & 1)], val);
    }
}

// ---------------- Kernel 4: GN+relu + 1x1 conv + bn2 + relu -> fp32 out -------
__global__ __launch_bounds__(256) void k_final(
    const float* __restrict__ cat,
    const float* __restrict__ raw2,
    const float* __restrict__ gnx_g, const float* __restrict__ gnx_b,
    const float* __restrict__ gny_g, const float* __restrict__ gny_b,
    const float* __restrict__ w2,
    const float* __restrict__ g2, const float* __restrict__ b2,
    const float* __restrict__ m2, const float* __restrict__ v2,
    float* __restrict__ out)
{
    __shared__ float wl[1024];
    __shared__ float sc2[64], sh2[64];
    __shared__ float cmean[16], crstd[16], cg[16], cb[16];
    int t = threadIdx.x;
    int pbase = blockIdx.x * 64;
    int b = pbase >> 16;
    for (int idx = t; idx < 1024; idx += 256) wl[idx] = w2[idx];
    if (t < 64) {
        float sc = g2[t] * rsqrtf(v2[t] + EPSF);
        sc2[t] = sc;
        sh2[t] = b2[t] - m2[t] * sc;
    }
    if (t < 16) {
        int branch = t >> 3; int cc = t & 7; int g = cc >> 2;
        int sidx = b * 4 + branch * 2 + g;
        float ss = raw2[sidx * 2], qq = raw2[sidx * 2 + 1];
        float mean = ss * (1.f / 262144.f);
        float var = qq * (1.f / 262144.f) - mean * mean;
        cmean[t] = mean;
        crstd[t] = rsqrtf(var + EPSF);
        cg[t] = branch ? gny_g[cc] : gnx_g[cc];
        cb[t] = branch ? gny_b[cc] : gnx_b[cc];
    }
    __syncthreads();
    int lane = t & 63, wq = t >> 6;
    int p = pbase + lane;
    int ij = p & 65535;
    float vv[16];
    const float* cp = &cat[(size_t)p * 16];
    #pragma unroll
    for (int c = 0; c < 16; ++c) {
        float x = (cp[c] - cmean[c]) * crstd[c] * cg[c] + cb[c];
        vv[c] = fmaxf(x, 0.f);
    }
    #pragma unroll
    for (int q = 0; q < 16; ++q) {
        int oc = wq + q * 4;
        float s = 0.f;
        #pragma unroll
        for (int c = 0; c < 16; ++c) s += vv[c] * wl[oc * 16 + c];
        float r = fmaxf(s * sc2[oc] + sh2[oc], 0.f);
        out[((size_t)(b * 64 + oc) << 16) + ij] = r;
    }
}

extern "C" void kernel_launch(void* const* d_in, const int* in_sizes, int n_in,
                              void* d_out, int out_size, void* d_ws, size_t ws_size,
                              hipStream_t stream) {
    const float* x       = (const float*)d_in[0];
    const float* conv1_w = (const float*)d_in[1];
    const float* bn1_g   = (const float*)d_in[2];
    const float* bn1_b   = (const float*)d_in[3];
    const float* bn1_m   = (const float*)d_in[4];
    const float* bn1_v   = (const float*)d_in[5];
    const float* offx_w  = (const float*)d_in[6];
    const float* offx_b  = (const float*)d_in[7];
    const float* gnoffx_g= (const float*)d_in[8];
    const float* gnoffx_b= (const float*)d_in[9];
    const float* dscx_w  = (const float*)d_in[10];
    const float* dscx_b  = (const float*)d_in[11];
    const float* gnx_g   = (const float*)d_in[12];
    const float* gnx_b   = (const float*)d_in[13];
    const float* offy_w  = (const float*)d_in[14];
    const float* offy_b  = (const float*)d_in[15];
    const float* gnoffy_g= (const float*)d_in[16];
    const float* gnoffy_b= (const float*)d_in[17];
    const float* dscy_w  = (const float*)d_in[18];
    const float* dscy_b  = (const float*)d_in[19];
    const float* gny_g   = (const float*)d_in[20];
    const float* gny_b   = (const float*)d_in[21];
    const float* conv2_w = (const float*)d_in[22];
    const float* bn2_g   = (const float*)d_in[23];
    const float* bn2_b   = (const float*)d_in[24];
    const float* bn2_m   = (const float*)d_in[25];
    const float* bn2_v   = (const float*)d_in[26];

    float* ws = (float*)d_ws;
    float* h        = ws;                       // 8,388,608
    float* offx     = h + 8388608;              // 1,310,720
    float* offy     = offx + 1310720;           // 1,310,720
    float* cat      = offy + 1310720;           // 2,097,152
    float* raw      = cat + 2097152;            // 40 offset sums
    float* raw2     = raw + 40;                 // 16 cat sums (zeroed as 64 total)

    k_conv1<<<1024, 256, 0, stream>>>(x, conv1_w, bn1_g, bn1_b, bn1_m, bn1_v, h, raw);
    k_offconv<<<256, 128, 0, stream>>>(h, offx_w, offy_w, offx_b, offy_b,
                                       offx, offy, raw);
    k_dsc<<<dim3(512, 2), 256, 0, stream>>>(h, offx, offy, raw,
                                            gnoffx_g, gnoffx_b, gnoffy_g, gnoffy_b,
                                            dscx_w, dscy_w, dscx_b, dscy_b,
                                            cat, raw2);
    k_final<<<2048, 256, 0, stream>>>(cat, raw2, gnx_g, gnx_b, gny_g, gny_b,
                                      conv2_w, bn2_g, bn2_b, bn2_m, bn2_v,
                                      (float*)d_out);
}

// Round 12
// 279.645 us; speedup vs baseline: 1.4514x; 1.2717x over previous
//
#include <hip/hip_runtime.h>
#include <hip/hip_bf16.h>

// h stored bf16 chunk layout [b][4][65536 px][16c] (entry = 32 B)
// k_offconv: implicit-GEMM MFMA 16x16x32 bf16, C[px][oc] = im2col(h) x W
// k_dsc: GN+tanh inline, 2-pt lerp (bf16 h -> fp32) + K=5 conv -> cat
// final: GN + 1x1 conv 16->64 + BN + ReLU -> fp32 NCHW

#define EPSF 1e-5f

typedef __attribute__((ext_vector_type(4))) float f4;
typedef __attribute__((ext_vector_type(8))) short bf8;
typedef __attribute__((ext_vector_type(8))) unsigned short us8;

static __device__ __forceinline__ unsigned pk2(float lo, float hi) {
    unsigned a = __float_as_uint(lo), b = __float_as_uint(hi);
    a = (a + 0x7FFFu + ((a >> 16) & 1)) >> 16;
    b = (b + 0x7FFFu + ((b >> 16) & 1)) >> 16;
    return a | (b << 16);
}
static __device__ __forceinline__ float bu2f(unsigned short u) {
    return __uint_as_float(((unsigned)u) << 16);
}

// ---------------- Kernel 1: conv1 + bn1 + relu -> h bf16 chunked --------------
__global__ __launch_bounds__(256) void k_conv1(
    const float* __restrict__ x, const float* __restrict__ w,
    const float* __restrict__ g, const float* __restrict__ bb,
    const float* __restrict__ m, const float* __restrict__ v,
    unsigned short* __restrict__ hb, float* __restrict__ statsraw)
{
    __shared__ float wl[27 * 64];            // [tap][oc]
    __shared__ float scale[64], shift[64];
    int t = threadIdx.x;
    if (blockIdx.x == 0 && t < 64) statsraw[t] = 0.f;   // zero raw(40)+raw2(16)
    for (int idx = t; idx < 1728; idx += 256) {
        int tap = idx >> 6, oc = idx & 63;
        wl[idx] = w[oc * 27 + tap];
    }
    if (t < 64) {
        float sc = g[t] * rsqrtf(v[t] + EPSF);
        scale[t] = sc; shift[t] = bb[t] - m[t] * sc;
    }
    __syncthreads();
    int lane = t & 63, wid = t >> 6;
    int blk = blockIdx.x;
    int b = blk >> 9;
    int rem = blk & 511;
    int i0 = (rem >> 2) * 2;
    int j0 = (rem & 3) * 64;
    int j = j0 + lane;
    f4 acc[2][4];
    #pragma unroll
    for (int r = 0; r < 2; ++r)
        #pragma unroll
        for (int q = 0; q < 4; ++q) acc[r][q] = (f4)0.f;
    #pragma unroll
    for (int ic = 0; ic < 3; ++ic) {
        #pragma unroll
        for (int dy = 0; dy < 3; ++dy) {
            const float* rowp[2]; bool vy[2];
            #pragma unroll
            for (int r = 0; r < 2; ++r) {
                int y = 2 * (i0 + r) + dy - 1;
                vy[r] = (unsigned)y < 512u;
                rowp[r] = x + ((size_t)(b * 3 + ic) * 512 + (vy[r] ? y : 0)) * 512;
            }
            #pragma unroll
            for (int dx = 0; dx < 3; ++dx) {
                int xx = 2 * j + dx - 1;
                bool vx = (unsigned)xx < 512u;
                int tap = ic * 9 + dy * 3 + dx;
                f4 w4[4];
                #pragma unroll
                for (int q = 0; q < 4; ++q)
                    w4[q] = *(const f4*)&wl[tap * 64 + wid * 16 + q * 4];
                #pragma unroll
                for (int r = 0; r < 2; ++r) {
                    float xv = (vy[r] && vx) ? rowp[r][xx] : 0.f;
                    #pragma unroll
                    for (int q = 0; q < 4; ++q) acc[r][q] += xv * w4[q];
                }
            }
        }
    }
    #pragma unroll
    for (int r = 0; r < 2; ++r) {
        size_t ij = (size_t)(i0 + r) * 256 + j;
        unsigned* hp = (unsigned*)(hb + ((size_t)(b * 4 + wid) * 65536 + ij) * 16);
        unsigned u[8];
        #pragma unroll
        for (int q = 0; q < 4; ++q) {
            f4 sc = *(const f4*)&scale[wid * 16 + q * 4];
            f4 sh = *(const f4*)&shift[wid * 16 + q * 4];
            f4 val = acc[r][q] * sc + sh;
            float v0 = fmaxf(val[0], 0.f), v1 = fmaxf(val[1], 0.f);
            float v2 = fmaxf(val[2], 0.f), v3 = fmaxf(val[3], 0.f);
            u[q * 2] = pk2(v0, v1);
            u[q * 2 + 1] = pk2(v2, v3);
        }
        *(uint4*)hp = make_uint4(u[0], u[1], u[2], u[3]);
        *(uint4*)(hp + 4) = make_uint4(u[4], u[5], u[6], u[7]);
    }
}

// ---------------- Kernel 2: offset convs via MFMA implicit GEMM ---------------
// grid 512 x 256 thr (4 waves); wave does 4 tiles of 16 px; N=32 (20 oc + pad).
// A[m=lane&15][k=quad*8+j], B[k=quad*8+j][n=lane&15], D[m=quad*4+reg][n=lane&15]
__global__ __launch_bounds__(256) void k_offconv(
    const unsigned short* __restrict__ hb,
    const float* __restrict__ wx, const float* __restrict__ wy,
    const float* __restrict__ bx, const float* __restrict__ by,
    float* __restrict__ offx, float* __restrict__ offy,
    float* __restrict__ raw)
{
    __shared__ short bstage[18432];          // [tap][kt][nt][lane][8] bf16, 36 KB
    __shared__ float wsum[4][2][16][2];
    int t = threadIdx.x;
    for (int idx = t; idx < 18432; idx += 256) {
        int jj = idx & 7;
        int lane_ = (idx >> 3) & 63;
        int nt = (idx >> 9) & 1;
        int kt = (idx >> 10) & 1;
        int tap = idx >> 11;
        int c = kt * 32 + (lane_ >> 4) * 8 + jj;
        int oc = nt * 16 + (lane_ & 15);
        float v = 0.f;
        if (oc < 10) v = wx[((size_t)oc * 64 + c) * 9 + tap];
        else if (oc < 20) v = wy[((size_t)(oc - 10) * 64 + c) * 9 + tap];
        unsigned uu = __float_as_uint(v);
        uu = (uu + 0x7FFFu + ((uu >> 16) & 1)) >> 16;
        bstage[idx] = (short)uu;
    }
    __syncthreads();
    int lane = t & 63, wid = t >> 6;
    int m = lane & 15, quad = lane >> 4;
    int blk = blockIdx.x;
    int b = blk >> 8;
    int oc_a = m;
    float bias_a = (oc_a < 10) ? bx[oc_a] : by[oc_a - 10];
    bool vb = (m < 4);
    float bias_b = vb ? by[6 + m] : 0.f;
    float s0 = 0.f, q0 = 0.f, s1 = 0.f, q1 = 0.f;
    const unsigned short* hb_b = hb + (size_t)b * 4 * 65536 * 16;
    #pragma unroll 1
    for (int tt = 0; tt < 4; ++tt) {
        int tile = (blk * 4 + wid) * 4 + tt;
        int p0 = tile * 16;
        int ij = p0 & 65535;
        int i = ij >> 8, j0 = ij & 255;
        f4 acc0 = (f4)0.f, acc1 = (f4)0.f;
        #pragma unroll
        for (int ky = 0; ky < 3; ++ky) {
            int y = i + ky - 1;
            if ((unsigned)y >= 256u) continue;
            #pragma unroll
            for (int kx = 0; kx < 3; ++kx) {
                int tap = ky * 3 + kx;
                int xc = j0 + m + kx - 1;
                bool vx = (unsigned)xc < 256u;
                int pix = y * 256 + (vx ? xc : 0);
                #pragma unroll
                for (int kt = 0; kt < 2; ++kt) {
                    int chunkk = kt * 2 + (quad >> 1);
                    const unsigned short* ap =
                        hb_b + ((size_t)chunkk * 65536 + pix) * 16 + (quad & 1) * 8;
                    bf8 a = vx ? *(const bf8*)ap : (bf8)0;
                    const short* bp = &bstage[(((tap * 2 + kt) * 2) * 64 + lane) * 8];
                    bf8 b0 = *(const bf8*)bp;
                    bf8 b1 = *(const bf8*)(bp + 512);
                    acc0 = __builtin_amdgcn_mfma_f32_16x16x32_bf16(a, b0, acc0, 0, 0, 0);
                    acc1 = __builtin_amdgcn_mfma_f32_16x16x32_bf16(a, b1, acc1, 0, 0, 0);
                }
            }
        }
        #pragma unroll
        for (int r = 0; r < 4; ++r) {
            int p = p0 + quad * 4 + r;
            float v0 = acc0[r] + bias_a;
            s0 += v0; q0 += v0 * v0;
            if (oc_a < 10) offx[(size_t)p * 10 + oc_a] = v0;
            else           offy[(size_t)p * 10 + oc_a - 10] = v0;
            if (vb) {
                float v1 = acc1[r] + bias_b;
                s1 += v1; q1 += v1 * v1;
                offy[(size_t)p * 10 + 6 + m] = v1;
            }
        }
    }
    s0 += __shfl_xor(s0, 16, 64); q0 += __shfl_xor(q0, 16, 64);
    s1 += __shfl_xor(s1, 16, 64); q1 += __shfl_xor(q1, 16, 64);
    s0 += __shfl_xor(s0, 32, 64); q0 += __shfl_xor(q0, 32, 64);
    s1 += __shfl_xor(s1, 32, 64); q1 += __shfl_xor(q1, 32, 64);
    if (quad == 0) {
        wsum[wid][0][m][0] = s0; wsum[wid][0][m][1] = q0;
        wsum[wid][1][m][0] = s1; wsum[wid][1][m][1] = q1;
    }
    __syncthreads();
    if (t < 20) {
        float ss = 0.f, qq = 0.f;
        if (t < 16) {
            #pragma unroll
            for (int w_ = 0; w_ < 4; ++w_) { ss += wsum[w_][0][t][0]; qq += wsum[w_][0][t][1]; }
        } else {
            #pragma unroll
            for (int w_ = 0; w_ < 4; ++w_) { ss += wsum[w_][1][t - 16][0]; qq += wsum[w_][1][t - 16][1]; }
        }
        int oc = t;                          // 0..15 and 16..19
        int branch = oc < 10 ? 0 : 1;
        int c = oc - branch * 10;
        int gid = branch * 10 + b * 5 + (c >> 1);
        atomicAdd(&raw[gid * 2], ss);
        atomicAdd(&raw[gid * 2 + 1], qq);
    }
}

// ---------------- Kernel 3: GN+tanh inline + 2pt-lerp (bf16) + deform conv ----
// block = 256; 64 j (lanes) x 4 i (4 waves x 1 row). grid (512,2).
__global__ __launch_bounds__(256) void k_dsc(
    const unsigned short* __restrict__ hb,
    const float* __restrict__ offx, const float* __restrict__ offy,
    const float* __restrict__ raw,
    const float* __restrict__ gx, const float* __restrict__ bxg,
    const float* __restrict__ gy, const float* __restrict__ byg,
    const float* __restrict__ wx_, const float* __restrict__ wy_,
    const float* __restrict__ bx_, const float* __restrict__ by_,
    float* __restrict__ cat,
    float* __restrict__ raw2)
{
    int branch = blockIdx.y;
    __shared__ float wl[2560];               // [k][c][oc8]
    __shared__ float bias[8];
    __shared__ float ws2[4][4];
    const float* wsrc = branch ? wy_ : wx_;
    int t = threadIdx.x;
    for (int idx = t; idx < 2560; idx += 256) {
        int oc = idx & 7;
        int rest = idx >> 3;                 // k*64 + c
        wl[idx] = wsrc[(size_t)oc * 320 + (rest & 63) * 5 + (rest >> 6)];
    }
    if (t < 8) bias[t] = (branch ? by_ : bx_)[t];
    __syncthreads();
    int lane = t & 63, wid = t >> 6;
    int blk = blockIdx.x;
    int b = blk >> 8;
    int rem = blk & 255;
    int i = (rem >> 2) * 4 + wid;
    int j = (rem & 3) * 64 + lane;
    const float* offarr = branch ? offy : offx;
    const float* goff = branch ? gy : gx;
    const float* boff = branch ? byg : bxg;
    int cbase = branch * 5;
    const int idxs[4] = {0, 1, 3, 4};
    float cum[5];
    {
        size_t p = (size_t)b * 65536 + (size_t)i * 256 + j;
        const float* op = offarr + p * 10 + cbase;
        float tv[4];
        #pragma unroll
        for (int u = 0; u < 4; ++u) {
            int c = cbase + idxs[u];
            int g = c >> 1;
            int sidx = branch * 10 + b * 5 + g;
            float ss = raw[sidx * 2], qq = raw[sidx * 2 + 1];
            float mean = ss * (1.f / 131072.f);
            float var = qq * (1.f / 131072.f) - mean * mean;
            float val = (op[idxs[u]] - mean) * rsqrtf(var + EPSF) * goff[c] + boff[c];
            tv[u] = tanhf(val);
        }
        cum[0] = tv[0] + tv[1]; cum[1] = tv[1]; cum[2] = 0.f;
        cum[3] = tv[2]; cum[4] = tv[2] + tv[3];
    }
    f4 acc0 = (f4)0.f, acc1 = (f4)0.f;
    #pragma unroll 1
    for (int k = 0; k < 5; ++k) {
        int pixA, pixB; float fr;
        if (branch == 0) {
            float yf = (float)i + cum[k];
            yf = fminf(fmaxf(yf, 0.f), 255.f);
            float y0 = floorf(yf);
            fr = yf - y0;
            int y0i = (int)y0;
            int y1i = min(y0i + 1, 255);
            int xi = min(max(j + k - 2, 0), 255);
            pixA = y0i * 256 + xi;
            pixB = y1i * 256 + xi;
        } else {
            float xf = (float)j + cum[k];
            xf = fminf(fmaxf(xf, 0.f), 255.f);
            float x0 = floorf(xf);
            fr = xf - x0;
            int x0i = (int)x0;
            int x1i = min(x0i + 1, 255);
            int yi = min(max(i + k - 2, 0), 255);
            pixA = yi * 256 + x0i;
            pixB = yi * 256 + x1i;
        }
        #pragma unroll 1
        for (int chunk = 0; chunk < 4; ++chunk) {
            const unsigned short* hc = hb + ((size_t)(b * 4 + chunk) * 65536) * 16;
            const float* wk = &wl[((size_t)k * 64 + chunk * 16) * 8];
            us8 aLo = *(const us8*)(hc + (size_t)pixA * 16);
            us8 aHi = *(const us8*)(hc + (size_t)pixA * 16 + 8);
            us8 bLo = *(const us8*)(hc + (size_t)pixB * 16);
            us8 bHi = *(const us8*)(hc + (size_t)pixB * 16 + 8);
            #pragma unroll
            for (int cq = 0; cq < 4; ++cq) {
                #pragma unroll
                for (int ci = 0; ci < 4; ++ci) {
                    int e = cq * 4 + ci;
                    float av = (e < 8) ? bu2f(aLo[e & 7]) : bu2f(aHi[e & 7]);
                    float bv = (e < 8) ? bu2f(bLo[e & 7]) : bu2f(bHi[e & 7]);
                    float vf = av + fr * (bv - av);
                    f4 w0 = *(const f4*)&wk[e * 8];
                    f4 w1 = *(const f4*)&wk[e * 8 + 4];
                    acc0 += vf * w0;
                    acc1 += vf * w1;
                }
            }
        }
    }
    float sg0 = 0.f, sq0 = 0.f, sg1 = 0.f, sq1 = 0.f;
    {
        size_t p = (size_t)b * 65536 + (size_t)i * 256 + j;
        f4 v0 = acc0 + *(const f4*)&bias[0];
        f4 v1 = acc1 + *(const f4*)&bias[4];
        *(f4*)&cat[p * 16 + branch * 8] = v0;
        *(f4*)&cat[p * 16 + branch * 8 + 4] = v1;
        #pragma unroll
        for (int e = 0; e < 4; ++e) {
            sg0 += v0[e]; sq0 += v0[e] * v0[e];
            sg1 += v1[e]; sq1 += v1[e] * v1[e];
        }
    }
    #pragma unroll
    for (int d = 32; d >= 1; d >>= 1) {
        sg0 += __shfl_xor(sg0, d, 64); sq0 += __shfl_xor(sq0, d, 64);
        sg1 += __shfl_xor(sg1, d, 64); sq1 += __shfl_xor(sq1, d, 64);
    }
    if (lane == 0) {
        ws2[wid][0] = sg0; ws2[wid][1] = sq0; ws2[wid][2] = sg1; ws2[wid][3] = sq1;
    }
    __syncthreads();
    if (t < 4) {
        float val = ws2[0][t] + ws2[1][t] + ws2[2][t] + ws2[3][t];
        int g0 = b * 4 + branch * 2;
        int gi = g0 + (t >> 1);
        atomicAdd(&raw2[gi * 2 + (t & 1)], val);
    }
}

// ---------------- Kernel 4: GN+relu + 1x1 conv + bn2 + relu -> fp32 out -------
__global__ __launch_bounds__(256) void k_final(
    const float* __restrict__ cat,
    const float* __restrict__ raw2,
    const float* __restrict__ gnx_g, const float* __restrict__ gnx_b,
    const float* __restrict__ gny_g, const float* __restrict__ gny_b,
    const float* __restrict__ w2,
    const float* __restrict__ g2, const float* __restrict__ b2,
    const float* __restrict__ m2, const float* __restrict__ v2,
    float* __restrict__ out)
{
    __shared__ float wl[1024];
    __shared__ float sc2[64], sh2[64];
    __shared__ float cmean[16], crstd[16], cg[16], cb[16];
    int t = threadIdx.x;
    int pbase = blockIdx.x * 64;
    int b = pbase >> 16;
    for (int idx = t; idx < 1024; idx += 256) wl[idx] = w2[idx];
    if (t < 64) {
        float sc = g2[t] * rsqrtf(v2[t] + EPSF);
        sc2[t] = sc;
        sh2[t] = b2[t] - m2[t] * sc;
    }
    if (t < 16) {
        int branch = t >> 3; int cc = t & 7; int g = cc >> 2;
        int sidx = b * 4 + branch * 2 + g;
        float ss = raw2[sidx * 2], qq = raw2[sidx * 2 + 1];
        float mean = ss * (1.f / 262144.f);
        float var = qq * (1.f / 262144.f) - mean * mean;
        cmean[t] = mean;
        crstd[t] = rsqrtf(var + EPSF);
        cg[t] = branch ? gny_g[cc] : gnx_g[cc];
        cb[t] = branch ? gny_b[cc] : gnx_b[cc];
    }
    __syncthreads();
    int lane = t & 63, wq = t >> 6;
    int p = pbase + lane;
    int ij = p & 65535;
    float vv[16];
    const float* cp = &cat[(size_t)p * 16];
    #pragma unroll
    for (int c = 0; c < 16; ++c) {
        float x = (cp[c] - cmean[c]) * crstd[c] * cg[c] + cb[c];
        vv[c] = fmaxf(x, 0.f);
    }
    #pragma unroll
    for (int q = 0; q < 16; ++q) {
        int oc = wq + q * 4;
        float s = 0.f;
        #pragma unroll
        for (int c = 0; c < 16; ++c) s += vv[c] * wl[oc * 16 + c];
        float r = fmaxf(s * sc2[oc] + sh2[oc], 0.f);
        out[((size_t)(b * 64 + oc) << 16) + ij] = r;
    }
}

extern "C" void kernel_launch(void* const* d_in, const int* in_sizes, int n_in,
                              void* d_out, int out_size, void* d_ws, size_t ws_size,
                              hipStream_t stream) {
    const float* x       = (const float*)d_in[0];
    const float* conv1_w = (const float*)d_in[1];
    const float* bn1_g   = (const float*)d_in[2];
    const float* bn1_b   = (const float*)d_in[3];
    const float* bn1_m   = (const float*)d_in[4];
    const float* bn1_v   = (const float*)d_in[5];
    const float* offx_w  = (const float*)d_in[6];
    const float* offx_b  = (const float*)d_in[7];
    const float* gnoffx_g= (const float*)d_in[8];
    const float* gnoffx_b= (const float*)d_in[9];
    const float* dscx_w  = (const float*)d_in[10];
    const float* dscx_b  = (const float*)d_in[11];
    const float* gnx_g   = (const float*)d_in[12];
    const float* gnx_b   = (const float*)d_in[13];
    const float* offy_w  = (const float*)d_in[14];
    const float* offy_b  = (const float*)d_in[15];
    const float* gnoffy_g= (const float*)d_in[16];
    const float* gnoffy_b= (const float*)d_in[17];
    const float* dscy_w  = (const float*)d_in[18];
    const float* dscy_b  = (const float*)d_in[19];
    const float* gny_g   = (const float*)d_in[20];
    const float* gny_b   = (const float*)d_in[21];
    const float* conv2_w = (const float*)d_in[22];
    const float* bn2_g   = (const float*)d_in[23];
    const float* bn2_b   = (const float*)d_in[24];
    const float* bn2_m   = (const float*)d_in[25];
    const float* bn2_v   = (const float*)d_in[26];

    float* ws = (float*)d_ws;
    unsigned short* hb = (unsigned short*)ws;   // 8,388,608 bf16 = 4,194,304 floats
    float* offx     = ws + 4194304;             // 1,310,720
    float* offy     = offx + 1310720;           // 1,310,720
    float* cat      = offy + 1310720;           // 2,097,152
    float* raw      = cat + 2097152;            // 40 offset sums
    float* raw2     = raw + 40;                 // 16 cat sums (zeroed as 64 total)

    k_conv1<<<1024, 256, 0, stream>>>(x, conv1_w, bn1_g, bn1_b, bn1_m, bn1_v, hb, raw);
    k_offconv<<<512, 256, 0, stream>>>(hb, offx_w, offy_w, offx_b, offy_b,
                                       offx, offy, raw);
    k_dsc<<<dim3(512, 2), 256, 0, stream>>>(hb, offx, offy, raw,
                                            gnoffx_g, gnoffx_b, gnoffy_g, gnoffy_b,
                                            dscx_w, dscy_w, dscx_b, dscy_b,
                                            cat, raw2);
    k_final<<<2048, 256, 0, stream>>>(cat, raw2, gnx_g, gnx_b, gny_g, gny_b,
                                      conv2_w, bn2_g, bn2_b, bn2_m, bn2_v,
                                      (float*)d_out);
}